// Round 3
// baseline (1202.856 us; speedup 1.0000x reference)
//
#include <hip/hip_runtime.h>
#include <hip/hip_bf16.h>

// GNN layer decomposition:
//   S = hidden @ Ws.T            (n_node x 32)   -- per-sub attn projection
//   R = rela_embed @ Wr.T        (n_rel  x 32)   -- per-rel attn projection
//   Q[b] = rela[q_rel[b]] @ Wqr.T + bqr (8 x 32) -- per-batch attn projection
//   per edge: alpha = sigmoid(dot(w_alpha, relu(S[sub]+R[rel]+Q[r_idx])) + b)
//             agg[obj] += alpha * (hidden[sub] + rela[rel])   (packed f32x2 atomic)
//   out = agg @ Wh.T             (n_node x 64)

typedef float v2f __attribute__((ext_vector_type(2)));

#if __has_builtin(__builtin_amdgcn_global_atomic_fadd_v2f32)
#define HAVE_PK_ATOMIC 1
#endif

#ifdef HAVE_PK_ATOMIC
typedef __attribute__((address_space(1))) v2f gv2f;
#endif

// One 8-byte RMW instead of two 4-byte RMWs when the HW packed atomic exists.
__device__ inline void atomic_pk_add(float* addr, float x, float y) {
#ifdef HAVE_PK_ATOMIC
    v2f val;
    val.x = x;
    val.y = y;
    gv2f* p = (gv2f*)(unsigned long long)(size_t)addr;  // int->ptr cast avoids addrspacecast issues
    __builtin_amdgcn_global_atomic_fadd_v2f32(p, val);  // result discarded -> no-return form
#else
    atomicAdd(addr, x);
    atomicAdd(addr + 1, y);
#endif
}

__global__ void proj32_kernel(const float* __restrict__ X, const float* __restrict__ W,
                              float* __restrict__ out, int nrows) {
    // out[n][k] = sum_d X[n][d] * W[k][d],  k<32, d<64
    __shared__ float wT[64 * 32];           // wT[d*32+k] = W[k*64+d]
    int tid = threadIdx.x;
    for (int i = tid; i < 32 * 64; i += 256) {
        int k = i >> 6, d = i & 63;
        wT[d * 32 + k] = W[i];
    }
    __syncthreads();
    int row = blockIdx.x * 8 + (tid >> 5);  // 8 rows per block
    int k = tid & 31;
    if (row >= nrows) return;
    const float4* X4 = (const float4*)(X + (size_t)row * 64);
    float acc = 0.f;
#pragma unroll
    for (int d4 = 0; d4 < 16; ++d4) {
        float4 x = X4[d4];                  // broadcast across the 32 lanes sharing row
        int d = d4 * 4;
        acc += x.x * wT[(d + 0) * 32 + k] + x.y * wT[(d + 1) * 32 + k]
             + x.z * wT[(d + 2) * 32 + k] + x.w * wT[(d + 3) * 32 + k];
    }
    out[(size_t)row * 32 + k] = acc;
}

__global__ void qproj_kernel(const int* __restrict__ q_rel, const float* __restrict__ rela,
                             const float* __restrict__ Wqr, const float* __restrict__ bqr,
                             float* __restrict__ Q, int batch) {
    int tid = threadIdx.x;
    int b = tid >> 5, k = tid & 31;
    if (b >= batch) return;
    int qr = q_rel[b];
    const float* x = rela + (size_t)qr * 64;
    const float* w = Wqr + (size_t)k * 64;
    float acc = bqr[k];
    for (int d = 0; d < 64; ++d) acc += w[d] * x[d];
    Q[b * 32 + k] = acc;
}

__global__ void edge_kernel(const int* __restrict__ edges, const float* __restrict__ S,
                            const float* __restrict__ R, const float* __restrict__ Q,
                            const float* __restrict__ hidden, const float* __restrict__ rela,
                            const float* __restrict__ w_alpha_w,
                            const float* __restrict__ w_alpha_b,
                            float* __restrict__ agg, int n_edge) {
    int tid = threadIdx.x;
    int lane = tid & 31;                     // 32 lanes cooperate on one edge
    int e = blockIdx.x * 8 + (tid >> 5);     // 8 edges per 256-thread block
    if (e >= n_edge) return;
    const int* er = edges + (size_t)e * 6;
    int ridx = er[0];
    int rel  = er[2];
    int sub  = er[4];
    int obj  = er[5];

    // attention logit: relu(S[sub]+R[rel]+Q[ridx]) . w_alpha
    float a = S[(size_t)sub * 32 + lane] + R[(size_t)rel * 32 + lane] + Q[ridx * 32 + lane];
    a = fmaxf(a, 0.f);
    float p = a * w_alpha_w[lane];
#pragma unroll
    for (int off = 16; off > 0; off >>= 1) p += __shfl_xor(p, off, 32);
    float alpha = 1.f / (1.f + __expf(-(p + w_alpha_b[0])));

    // message = alpha * (hidden[sub] + rela[rel]); each lane handles 2 floats
    const float2* h2 = (const float2*)hidden + (size_t)sub * 32 + lane;
    const float2* r2 = (const float2*)rela + (size_t)rel * 32 + lane;
    float2 h = *h2;
    float2 r = *r2;
    float* dst = agg + (size_t)obj * 64 + lane * 2;
    atomic_pk_add(dst, alpha * (h.x + r.x), alpha * (h.y + r.y));
}

__global__ void outgemm_kernel(const float* __restrict__ agg, const float* __restrict__ Wh,
                               float* __restrict__ out, int nrows) {
    // out[n][j] = sum_d agg[n][d] * Wh[j][d],  j<64, d<64
    __shared__ float wT[64 * 64];           // wT[d*64+j] = Wh[j*64+d]
    int tid = threadIdx.x;
    for (int i = tid; i < 64 * 64; i += 256) {
        int j = i >> 6, d = i & 63;
        wT[d * 64 + j] = Wh[i];
    }
    __syncthreads();
    int row = blockIdx.x * 4 + (tid >> 6);  // 4 rows per block
    int j = tid & 63;
    if (row >= nrows) return;
    const float4* A4 = (const float4*)(agg + (size_t)row * 64);
    float acc = 0.f;
#pragma unroll
    for (int d4 = 0; d4 < 16; ++d4) {
        float4 x = A4[d4];
        int d = d4 * 4;
        acc += x.x * wT[(d + 0) * 64 + j] + x.y * wT[(d + 1) * 64 + j]
             + x.z * wT[(d + 2) * 64 + j] + x.w * wT[(d + 3) * 64 + j];
    }
    out[(size_t)row * 64 + j] = acc;
}

extern "C" void kernel_launch(void* const* d_in, const int* in_sizes, int n_in,
                              void* d_out, int out_size, void* d_ws, size_t ws_size,
                              hipStream_t stream) {
    // inputs (setup_inputs order):
    // 0 q_sub (unused), 1 q_rel, 2 hidden, 3 edges, 4 nodes (unused),
    // 5 old_nodes_new_idx (unused), 6 batchsize, 7 rela_embed,
    // 8 Ws, 9 Wr, 10 Wqr, 11 bqr, 12 w_alpha_w, 13 w_alpha_b, 14 Wh
    const int*   q_rel     = (const int*)d_in[1];
    const float* hidden    = (const float*)d_in[2];
    const int*   edges     = (const int*)d_in[3];
    const float* rela      = (const float*)d_in[7];
    const float* Ws        = (const float*)d_in[8];
    const float* Wr        = (const float*)d_in[9];
    const float* Wqr       = (const float*)d_in[10];
    const float* bqr       = (const float*)d_in[11];
    const float* w_alpha_w = (const float*)d_in[12];
    const float* w_alpha_b = (const float*)d_in[13];
    const float* Wh        = (const float*)d_in[14];

    int n_node = in_sizes[2] / 64;
    int n_edge = in_sizes[3] / 6;
    int n_rel  = in_sizes[7] / 64;
    int batch  = in_sizes[1];

    // workspace layout (floats)
    float* S   = (float*)d_ws;                    // n_node*32
    float* agg = S + (size_t)n_node * 32;         // n_node*64
    float* R   = agg + (size_t)n_node * 64;       // n_rel*32
    float* Q   = R + (size_t)n_rel * 32;          // batch*32

    (void)hipMemsetAsync(agg, 0, (size_t)n_node * 64 * sizeof(float), stream);

    proj32_kernel<<<(n_node + 7) / 8, 256, 0, stream>>>(hidden, Ws, S, n_node);
    proj32_kernel<<<(n_rel + 7) / 8, 256, 0, stream>>>(rela, Wr, R, n_rel);
    qproj_kernel<<<1, 256, 0, stream>>>(q_rel, rela, Wqr, bqr, Q, batch);

    edge_kernel<<<(n_edge + 7) / 8, 256, 0, stream>>>(edges, S, R, Q, hidden, rela,
                                                      w_alpha_w, w_alpha_b, agg, n_edge);

    outgemm_kernel<<<(n_node + 3) / 4, 256, 0, stream>>>(agg, Wh, (float*)d_out, n_node);
}

// Round 4
// 854.828 us; speedup vs baseline: 1.4071x; 1.4071x over previous
//
#include <hip/hip_runtime.h>
#include <hip/hip_bf16.h>

// Atomic-free GNN layer via counting-sort by obj:
//   S = hidden @ Ws.T, R = rela @ Wr.T, Q[b] = rela[q_rel[b]] @ Wqr.T + bqr
//   alpha[e] = sigmoid(w_alpha . relu(S[sub]+R[rel]+Q[r_idx]) + b)   (+ histogram of obj)
//   exclusive scan of counts -> offs/cur
//   scatter rec[pos] = {alpha, sub|rel<<17} sorted by obj  (8B records, no f32 RMW)
//   reduce: per node, sum alpha*(hidden[sub]+rela[rel]) over its segment -> d_out (as agg)
//   outgemm_inplace: d_out rows <- d_out rows @ Wh.T

__global__ void proj32_kernel(const float* __restrict__ X, const float* __restrict__ W,
                              float* __restrict__ out, int nrows) {
    // out[n][k] = sum_d X[n][d] * W[k][d],  k<32, d<64
    __shared__ float wT[64 * 32];
    int tid = threadIdx.x;
    for (int i = tid; i < 32 * 64; i += 256) {
        int k = i >> 6, d = i & 63;
        wT[d * 32 + k] = W[i];
    }
    __syncthreads();
    int row = blockIdx.x * 8 + (tid >> 5);
    int k = tid & 31;
    if (row >= nrows) return;
    const float4* X4 = (const float4*)(X + (size_t)row * 64);
    float acc = 0.f;
#pragma unroll
    for (int d4 = 0; d4 < 16; ++d4) {
        float4 x = X4[d4];
        int d = d4 * 4;
        acc += x.x * wT[(d + 0) * 32 + k] + x.y * wT[(d + 1) * 32 + k]
             + x.z * wT[(d + 2) * 32 + k] + x.w * wT[(d + 3) * 32 + k];
    }
    out[(size_t)row * 32 + k] = acc;
}

__global__ void qproj_kernel(const int* __restrict__ q_rel, const float* __restrict__ rela,
                             const float* __restrict__ Wqr, const float* __restrict__ bqr,
                             float* __restrict__ Q, int batch) {
    int tid = threadIdx.x;
    int b = tid >> 5, k = tid & 31;
    if (b >= batch) return;
    int qr = q_rel[b];
    const float* x = rela + (size_t)qr * 64;
    const float* w = Wqr + (size_t)k * 64;
    float acc = bqr[k];
    for (int d = 0; d < 64; ++d) acc += w[d] * x[d];
    Q[b * 32 + k] = acc;
}

__global__ void alpha_hist_kernel(const int* __restrict__ edges, const float* __restrict__ S,
                                  const float* __restrict__ R, const float* __restrict__ Q,
                                  const float* __restrict__ w_alpha_w,
                                  const float* __restrict__ w_alpha_b,
                                  float* __restrict__ alpha, int* __restrict__ counts,
                                  int n_edge) {
    int tid = threadIdx.x;
    int lane = tid & 31;
    int e = blockIdx.x * 8 + (tid >> 5);
    if (e >= n_edge) return;
    const int* er = edges + (size_t)e * 6;
    int ridx = er[0];
    int rel  = er[2];
    int sub  = er[4];
    int obj  = er[5];
    float a = S[(size_t)sub * 32 + lane] + R[(size_t)rel * 32 + lane] + Q[ridx * 32 + lane];
    a = fmaxf(a, 0.f);
    float p = a * w_alpha_w[lane];
#pragma unroll
    for (int off = 16; off > 0; off >>= 1) p += __shfl_xor(p, off, 32);
    if (lane == 0) {
        alpha[e] = 1.f / (1.f + __expf(-(p + w_alpha_b[0])));
        atomicAdd(&counts[obj], 1);   // int atomic on 400KB L2-resident table
    }
}

// single-block exclusive scan of counts[0..N) -> offs[0..N], cur[0..N)
__global__ void scan_kernel(const int* __restrict__ counts, int* __restrict__ offs,
                            int* __restrict__ cur, int N) {
    __shared__ int s[1024];
    __shared__ int carry_s;
    const int tid = threadIdx.x;
    if (tid == 0) carry_s = 0;
    __syncthreads();
    const int CHUNK = 1024 * 8;
    for (int base = 0; base < N; base += CHUNK) {
        int idx0 = base + tid * 8;
        int v[8];
        int mysum = 0;
#pragma unroll
        for (int k = 0; k < 8; ++k) {
            int idx = idx0 + k;
            v[k] = (idx < N) ? counts[idx] : 0;
            mysum += v[k];
        }
        s[tid] = mysum;
        __syncthreads();
        for (int off = 1; off < 1024; off <<= 1) {
            int t = (tid >= off) ? s[tid - off] : 0;
            __syncthreads();
            s[tid] += t;
            __syncthreads();
        }
        int run = carry_s + s[tid] - mysum;  // exclusive prefix of this thread's 1st elem
#pragma unroll
        for (int k = 0; k < 8; ++k) {
            int idx = idx0 + k;
            if (idx < N) { offs[idx] = run; cur[idx] = run; }
            run += v[k];
        }
        __syncthreads();
        if (tid == 0) carry_s += s[1023];
        __syncthreads();
    }
    if (tid == 0) offs[N] = carry_s;
}

__global__ void scatter_kernel(const int* __restrict__ edges, const float* __restrict__ alpha,
                               int* __restrict__ cur, float2* __restrict__ rec, int n_edge) {
    int e = blockIdx.x * 256 + threadIdx.x;
    if (e >= n_edge) return;
    const int* er = edges + (size_t)e * 6;
    int rel = er[2];
    int sub = er[4];
    int obj = er[5];
    int pos = atomicAdd(&cur[obj], 1);
    float2 r;
    r.x = alpha[e];
    r.y = __int_as_float(sub | (rel << 17));  // sub<2^17, rel<2^9
    rec[pos] = r;
}

// one 64-lane wave per node (lane = output dim); plain store, no atomics
__global__ void reduce_kernel(const float2* __restrict__ rec, const int* __restrict__ offs,
                              const float* __restrict__ hidden, const float* __restrict__ rela,
                              float* __restrict__ out, int n_node) {
    int lane = threadIdx.x & 63;
    int node = blockIdx.x * 4 + (threadIdx.x >> 6);
    if (node >= n_node) return;
    int start = offs[node], end = offs[node + 1];
    float acc = 0.f;
    for (int i = start; i < end; i += 64) {
        int m = end - i;
        if (m > 64) m = 64;
        float a = 0.f;
        int pk = 0;
        if (lane < m) {
            float2 r = rec[i + lane];
            a = r.x;
            pk = __float_as_int(r.y);
        }
#pragma unroll 4
        for (int j = 0; j < m; ++j) {
            float aj = __shfl(a, j, 64);
            int pkj = __shfl(pk, j, 64);
            int sub = pkj & 0x1FFFF;
            int rel = pkj >> 17;
            acc += aj * (hidden[(size_t)sub * 64 + lane] + rela[(size_t)rel * 64 + lane]);
        }
    }
    out[(size_t)node * 64 + lane] = acc;
}

// in-place: io rows <- io rows @ Wh.T  (32 rows per block, staged through LDS)
__global__ void outgemm_inplace_kernel(const float* __restrict__ Wh, float* __restrict__ io,
                                       int n_node) {
    __shared__ float wT[64 * 64];   // wT[d*64+j] = Wh[j*64+d]
    __shared__ float arows[4 * 64];
    int tid = threadIdx.x;
    for (int i = tid; i < 64 * 64; i += 256) {
        int j = i >> 6, d = i & 63;
        wT[d * 64 + j] = Wh[i];
    }
    int r = tid >> 6, j = tid & 63;
    for (int g = 0; g < 8; ++g) {
        int gbase = blockIdx.x * 32 + g * 4;          // first row of this 4-row group
        __syncthreads();                               // wT ready / prev readers done
        if ((size_t)gbase * 64 + tid < (size_t)n_node * 64)
            arows[tid] = io[(size_t)gbase * 64 + tid];
        __syncthreads();
        int row = gbase + r;
        if (row < n_node) {
            float acc = 0.f;
#pragma unroll
            for (int d4 = 0; d4 < 16; ++d4) {
                int d = d4 * 4;
                float4 m4 = *(const float4*)&arows[r * 64 + d];  // broadcast within wave
                acc += m4.x * wT[(d + 0) * 64 + j] + m4.y * wT[(d + 1) * 64 + j]
                     + m4.z * wT[(d + 2) * 64 + j] + m4.w * wT[(d + 3) * 64 + j];
            }
            io[(size_t)row * 64 + j] = acc;
        }
    }
}

extern "C" void kernel_launch(void* const* d_in, const int* in_sizes, int n_in,
                              void* d_out, int out_size, void* d_ws, size_t ws_size,
                              hipStream_t stream) {
    const int*   q_rel     = (const int*)d_in[1];
    const float* hidden    = (const float*)d_in[2];
    const int*   edges     = (const int*)d_in[3];
    const float* rela      = (const float*)d_in[7];
    const float* Ws        = (const float*)d_in[8];
    const float* Wr        = (const float*)d_in[9];
    const float* Wqr       = (const float*)d_in[10];
    const float* bqr       = (const float*)d_in[11];
    const float* w_alpha_w = (const float*)d_in[12];
    const float* w_alpha_b = (const float*)d_in[13];
    const float* Wh        = (const float*)d_in[14];

    int n_node = in_sizes[2] / 64;
    int n_edge = in_sizes[3] / 6;
    int n_rel  = in_sizes[7] / 64;
    int batch  = in_sizes[1];

    // workspace layout (~38 MB)
    float* S      = (float*)d_ws;                         // n_node*32
    float* R      = S + (size_t)n_node * 32;              // n_rel*32
    float* Q      = R + (size_t)n_rel * 32;               // batch*32
    float* alpha  = Q + (size_t)batch * 32;               // n_edge
    int*   counts = (int*)(alpha + n_edge);               // n_node
    int*   offs   = counts + n_node;                      // n_node+1
    int*   cur    = offs + n_node + 1;                    // n_node
    size_t rec_off = (size_t)(cur + n_node - (int*)d_ws); // in int units
    rec_off = (rec_off + 3) & ~(size_t)3;                 // align 16B
    float2* rec   = (float2*)((int*)d_ws + rec_off);      // n_edge float2

    (void)hipMemsetAsync(counts, 0, (size_t)n_node * sizeof(int), stream);

    proj32_kernel<<<(n_node + 7) / 8, 256, 0, stream>>>(hidden, Ws, S, n_node);
    proj32_kernel<<<(n_rel + 7) / 8, 256, 0, stream>>>(rela, Wr, R, n_rel);
    qproj_kernel<<<1, 256, 0, stream>>>(q_rel, rela, Wqr, bqr, Q, batch);

    alpha_hist_kernel<<<(n_edge + 7) / 8, 256, 0, stream>>>(edges, S, R, Q, w_alpha_w,
                                                            w_alpha_b, alpha, counts, n_edge);
    scan_kernel<<<1, 1024, 0, stream>>>(counts, offs, cur, n_node);
    scatter_kernel<<<(n_edge + 255) / 256, 256, 0, stream>>>(edges, alpha, cur, rec, n_edge);
    reduce_kernel<<<(n_node + 3) / 4, 256, 0, stream>>>(rec, offs, hidden, rela,
                                                        (float*)d_out, n_node);
    outgemm_inplace_kernel<<<(n_node + 31) / 32, 256, 0, stream>>>(Wh, (float*)d_out, n_node);
}

// Round 5
// 633.691 us; speedup vs baseline: 1.8982x; 1.3490x over previous
//
#include <hip/hip_runtime.h>
#include <hip/hip_bf16.h>

// Atomic-free GNN layer via counting-sort by obj:
//   S = hidden @ Ws.T, R = rela @ Wr.T, Q[b] = rela[q_rel[b]] @ Wqr.T + bqr
//   alpha[e] = sigmoid(w_alpha . relu(S[sub]+R[rel]+Q[r_idx]) + b)   (+ histogram of obj)
//   multi-block exclusive scan of counts -> offs/cur
//   scatter rec[pos] = {alpha, sub|rel<<17} sorted by obj  (8B records, no f32 RMW)
//   reduce: per node, sum alpha*(hidden[sub]+rela[rel]) over its segment -> d_out (as agg)
//   outgemm_inplace: d_out rows <- d_out rows @ Wh.T

__global__ void proj32_kernel(const float* __restrict__ X, const float* __restrict__ W,
                              float* __restrict__ out, int nrows) {
    // out[n][k] = sum_d X[n][d] * W[k][d],  k<32, d<64
    __shared__ float wT[64 * 32];
    int tid = threadIdx.x;
    for (int i = tid; i < 32 * 64; i += 256) {
        int k = i >> 6, d = i & 63;
        wT[d * 32 + k] = W[i];
    }
    __syncthreads();
    int row = blockIdx.x * 8 + (tid >> 5);
    int k = tid & 31;
    if (row >= nrows) return;
    const float4* X4 = (const float4*)(X + (size_t)row * 64);
    float acc = 0.f;
#pragma unroll
    for (int d4 = 0; d4 < 16; ++d4) {
        float4 x = X4[d4];
        int d = d4 * 4;
        acc += x.x * wT[(d + 0) * 32 + k] + x.y * wT[(d + 1) * 32 + k]
             + x.z * wT[(d + 2) * 32 + k] + x.w * wT[(d + 3) * 32 + k];
    }
    out[(size_t)row * 32 + k] = acc;
}

__global__ void qproj_kernel(const int* __restrict__ q_rel, const float* __restrict__ rela,
                             const float* __restrict__ Wqr, const float* __restrict__ bqr,
                             float* __restrict__ Q, int batch) {
    int tid = threadIdx.x;
    int b = tid >> 5, k = tid & 31;
    if (b >= batch) return;
    int qr = q_rel[b];
    const float* x = rela + (size_t)qr * 64;
    const float* w = Wqr + (size_t)k * 64;
    float acc = bqr[k];
    for (int d = 0; d < 64; ++d) acc += w[d] * x[d];
    Q[b * 32 + k] = acc;
}

// 16 lanes per edge, float2 gathers; 16 edges per 256-thread block.
__global__ void alpha_hist_kernel(const int* __restrict__ edges, const float2* __restrict__ S2,
                                  const float2* __restrict__ R2, const float2* __restrict__ Q2,
                                  const float2* __restrict__ w2,
                                  const float* __restrict__ w_alpha_b,
                                  float* __restrict__ alpha, int* __restrict__ counts,
                                  int n_edge) {
    int tid = threadIdx.x;
    int lane = tid & 15;
    int e = blockIdx.x * 16 + (tid >> 4);
    if (e >= n_edge) return;
    const int* er = edges + (size_t)e * 6;
    int ridx = er[0];
    int rel  = er[2];
    int sub  = er[4];
    int obj  = er[5];
    float2 s = S2[(size_t)sub * 16 + lane];
    float2 r = R2[(size_t)rel * 16 + lane];
    float2 q = Q2[ridx * 16 + lane];
    float a0 = fmaxf(s.x + r.x + q.x, 0.f);
    float a1 = fmaxf(s.y + r.y + q.y, 0.f);
    float2 w = w2[lane];
    float p = a0 * w.x + a1 * w.y;
#pragma unroll
    for (int off = 8; off > 0; off >>= 1) p += __shfl_xor(p, off, 16);
    if (lane == 0) {
        alpha[e] = 1.f / (1.f + __expf(-(p + w_alpha_b[0])));
        atomicAdd(&counts[obj], 1);   // int atomic on 400KB L2-resident table
    }
}

// ---- multi-block exclusive scan (counts[0..N) -> offs[0..N], cur[0..N)) ----
#define SCAN_CHUNK 1024

__global__ void scan_partial_kernel(const int* __restrict__ counts, int* __restrict__ bsum,
                                    int N) {
    __shared__ int s[256];
    int base = blockIdx.x * SCAN_CHUNK;
    int tid = threadIdx.x;
    int sum = 0;
#pragma unroll
    for (int k = 0; k < 4; ++k) {
        int idx = base + k * 256 + tid;
        if (idx < N) sum += counts[idx];
    }
    s[tid] = sum;
    __syncthreads();
    for (int off = 128; off > 0; off >>= 1) {
        if (tid < off) s[tid] += s[tid + off];
        __syncthreads();
    }
    if (tid == 0) bsum[blockIdx.x] = s[0];
}

__global__ void scan_bsum_kernel(int* __restrict__ bsum, int* __restrict__ offs, int B, int N) {
    // single block of 1024: exclusive scan of bsum (B <= 1024), total -> offs[N]
    __shared__ int s[1024];
    int tid = threadIdx.x;
    int v = (tid < B) ? bsum[tid] : 0;
    s[tid] = v;
    __syncthreads();
    for (int off = 1; off < 1024; off <<= 1) {
        int t = (tid >= off) ? s[tid - off] : 0;
        __syncthreads();
        s[tid] += t;
        __syncthreads();
    }
    if (tid < B) bsum[tid] = s[tid] - v;   // exclusive block prefix
    if (tid == 0) offs[N] = s[1023];       // grand total
}

__global__ void scan_final_kernel(const int* __restrict__ counts, const int* __restrict__ bsum,
                                  int* __restrict__ offs, int* __restrict__ cur, int N) {
    __shared__ int s[256];
    int base = blockIdx.x * SCAN_CHUNK;
    int tid = threadIdx.x;
    int v[4];
    int sum = 0;
#pragma unroll
    for (int k = 0; k < 4; ++k) {
        int idx = base + tid * 4 + k;
        v[k] = (idx < N) ? counts[idx] : 0;
        sum += v[k];
    }
    s[tid] = sum;
    __syncthreads();
    for (int off = 1; off < 256; off <<= 1) {
        int t = (tid >= off) ? s[tid - off] : 0;
        __syncthreads();
        s[tid] += t;
        __syncthreads();
    }
    int run = bsum[blockIdx.x] + s[tid] - sum;
#pragma unroll
    for (int k = 0; k < 4; ++k) {
        int idx = base + tid * 4 + k;
        if (idx < N) { offs[idx] = run; cur[idx] = run; }
        run += v[k];
    }
}

__global__ void scatter_kernel(const int* __restrict__ edges, const float* __restrict__ alpha,
                               int* __restrict__ cur, float2* __restrict__ rec, int n_edge) {
    int e = blockIdx.x * 256 + threadIdx.x;
    if (e >= n_edge) return;
    const int* er = edges + (size_t)e * 6;
    int rel = er[2];
    int sub = er[4];
    int obj = er[5];
    int pos = atomicAdd(&cur[obj], 1);
    float2 r;
    r.x = alpha[e];
    r.y = __int_as_float(sub | (rel << 17));  // sub<2^17, rel<2^9
    rec[pos] = r;
}

// one 64-lane wave per node (lane = output dim); plain store, no atomics
__global__ void reduce_kernel(const float2* __restrict__ rec, const int* __restrict__ offs,
                              const float* __restrict__ hidden, const float* __restrict__ rela,
                              float* __restrict__ out, int n_node) {
    int lane = threadIdx.x & 63;
    int node = blockIdx.x * 4 + (threadIdx.x >> 6);
    if (node >= n_node) return;
    int start = offs[node], end = offs[node + 1];
    float acc = 0.f;
    for (int i = start; i < end; i += 64) {
        int m = end - i;
        if (m > 64) m = 64;
        float a = 0.f;
        int pk = 0;
        if (lane < m) {
            float2 r = rec[i + lane];
            a = r.x;
            pk = __float_as_int(r.y);
        }
#pragma unroll 4
        for (int j = 0; j < m; ++j) {
            float aj = __shfl(a, j, 64);
            int pkj = __shfl(pk, j, 64);
            int sub = pkj & 0x1FFFF;
            int rel = pkj >> 17;
            acc += aj * (hidden[(size_t)sub * 64 + lane] + rela[(size_t)rel * 64 + lane]);
        }
    }
    out[(size_t)node * 64 + lane] = acc;
}

// in-place: io rows <- io rows @ Wh.T  (32 rows per block, staged through LDS)
__global__ void outgemm_inplace_kernel(const float* __restrict__ Wh, float* __restrict__ io,
                                       int n_node) {
    __shared__ float wT[64 * 64];   // wT[d*64+j] = Wh[j*64+d]
    __shared__ float arows[4 * 64];
    int tid = threadIdx.x;
    for (int i = tid; i < 64 * 64; i += 256) {
        int j = i >> 6, d = i & 63;
        wT[d * 64 + j] = Wh[i];
    }
    int r = tid >> 6, j = tid & 63;
    for (int g = 0; g < 8; ++g) {
        int gbase = blockIdx.x * 32 + g * 4;
        __syncthreads();
        if ((size_t)gbase * 64 + tid < (size_t)n_node * 64)
            arows[tid] = io[(size_t)gbase * 64 + tid];
        __syncthreads();
        int row = gbase + r;
        if (row < n_node) {
            float acc = 0.f;
#pragma unroll
            for (int d4 = 0; d4 < 16; ++d4) {
                int d = d4 * 4;
                float4 m4 = *(const float4*)&arows[r * 64 + d];
                acc += m4.x * wT[(d + 0) * 64 + j] + m4.y * wT[(d + 1) * 64 + j]
                     + m4.z * wT[(d + 2) * 64 + j] + m4.w * wT[(d + 3) * 64 + j];
            }
            io[(size_t)row * 64 + j] = acc;
        }
    }
}

extern "C" void kernel_launch(void* const* d_in, const int* in_sizes, int n_in,
                              void* d_out, int out_size, void* d_ws, size_t ws_size,
                              hipStream_t stream) {
    const int*   q_rel     = (const int*)d_in[1];
    const float* hidden    = (const float*)d_in[2];
    const int*   edges     = (const int*)d_in[3];
    const float* rela      = (const float*)d_in[7];
    const float* Ws        = (const float*)d_in[8];
    const float* Wr        = (const float*)d_in[9];
    const float* Wqr       = (const float*)d_in[10];
    const float* bqr       = (const float*)d_in[11];
    const float* w_alpha_w = (const float*)d_in[12];
    const float* w_alpha_b = (const float*)d_in[13];
    const float* Wh        = (const float*)d_in[14];

    int n_node = in_sizes[2] / 64;
    int n_edge = in_sizes[3] / 6;
    int n_rel  = in_sizes[7] / 64;
    int batch  = in_sizes[1];

    int n_sblk = (n_node + SCAN_CHUNK - 1) / SCAN_CHUNK;   // scan blocks (<=1024)

    // workspace layout (~54 MB)
    float* S      = (float*)d_ws;                         // n_node*32
    float* R      = S + (size_t)n_node * 32;              // n_rel*32
    float* Q      = R + (size_t)n_rel * 32;               // batch*32
    float* alpha  = Q + (size_t)batch * 32;               // n_edge
    int*   counts = (int*)(alpha + n_edge);               // n_node
    int*   offs   = counts + n_node;                      // n_node+1
    int*   cur    = offs + n_node + 1;                    // n_node
    int*   bsum   = cur + n_node;                         // n_sblk
    size_t rec_off = (size_t)(bsum + n_sblk - (int*)d_ws);
    rec_off = (rec_off + 3) & ~(size_t)3;                 // align 16B
    float2* rec   = (float2*)((int*)d_ws + rec_off);      // n_edge float2

    (void)hipMemsetAsync(counts, 0, (size_t)n_node * sizeof(int), stream);

    proj32_kernel<<<(n_node + 7) / 8, 256, 0, stream>>>(hidden, Ws, S, n_node);
    proj32_kernel<<<(n_rel + 7) / 8, 256, 0, stream>>>(rela, Wr, R, n_rel);
    qproj_kernel<<<1, 256, 0, stream>>>(q_rel, rela, Wqr, bqr, Q, batch);

    alpha_hist_kernel<<<(n_edge + 15) / 16, 256, 0, stream>>>(
        edges, (const float2*)S, (const float2*)R, (const float2*)Q,
        (const float2*)w_alpha_w, w_alpha_b, alpha, counts, n_edge);

    scan_partial_kernel<<<n_sblk, 256, 0, stream>>>(counts, bsum, n_node);
    scan_bsum_kernel<<<1, 1024, 0, stream>>>(bsum, offs, n_sblk, n_node);
    scan_final_kernel<<<n_sblk, 256, 0, stream>>>(counts, bsum, offs, cur, n_node);

    scatter_kernel<<<(n_edge + 255) / 256, 256, 0, stream>>>(edges, alpha, cur, rec, n_edge);
    reduce_kernel<<<(n_node + 3) / 4, 256, 0, stream>>>(rec, offs, hidden, rela,
                                                        (float*)d_out, n_node);
    outgemm_inplace_kernel<<<(n_node + 31) / 32, 256, 0, stream>>>(Wh, (float*)d_out, n_node);
}

// Round 6
// 570.099 us; speedup vs baseline: 2.1099x; 1.1115x over previous
//
#include <hip/hip_runtime.h>
#include <hip/hip_bf16.h>

// Atomic-free aggregation via counting-sort by obj:
//   S = hidden @ Ws.T, R = rela @ Wr.T, Q[b] = rela[q_rel[b]] @ Wqr.T + bqr
//   hist: counts[obj]++                                   (int atomics, L2-resident)
//   multi-block exclusive scan of counts -> offs/cur
//   alpha+scatter fused: alpha = sigmoid(...); pos = cur[obj]++;
//                        rec[pos] = {alpha, sub|rel<<17}   (8B records, no f32 RMW)
//   reduce: per node, sum alpha*(hidden[sub]+rela[rel]) over its segment -> d_out
//   outgemm_inplace: d_out rows <- d_out rows @ Wh.T

__global__ void proj32_kernel(const float* __restrict__ X, const float* __restrict__ W,
                              float* __restrict__ out, int nrows) {
    // out[n][k] = sum_d X[n][d] * W[k][d],  k<32, d<64
    __shared__ float wT[64 * 32];
    int tid = threadIdx.x;
    for (int i = tid; i < 32 * 64; i += 256) {
        int k = i >> 6, d = i & 63;
        wT[d * 32 + k] = W[i];
    }
    __syncthreads();
    int row = blockIdx.x * 8 + (tid >> 5);
    int k = tid & 31;
    if (row >= nrows) return;
    const float4* X4 = (const float4*)(X + (size_t)row * 64);
    float acc = 0.f;
#pragma unroll
    for (int d4 = 0; d4 < 16; ++d4) {
        float4 x = X4[d4];
        int d = d4 * 4;
        acc += x.x * wT[(d + 0) * 32 + k] + x.y * wT[(d + 1) * 32 + k]
             + x.z * wT[(d + 2) * 32 + k] + x.w * wT[(d + 3) * 32 + k];
    }
    out[(size_t)row * 32 + k] = acc;
}

__global__ void qproj_kernel(const int* __restrict__ q_rel, const float* __restrict__ rela,
                             const float* __restrict__ Wqr, const float* __restrict__ bqr,
                             float* __restrict__ Q, int batch) {
    int tid = threadIdx.x;
    int b = tid >> 5, k = tid & 31;
    if (b >= batch) return;
    int qr = q_rel[b];
    const float* x = rela + (size_t)qr * 64;
    const float* w = Wqr + (size_t)k * 64;
    float acc = bqr[k];
    for (int d = 0; d < 64; ++d) acc += w[d] * x[d];
    Q[b * 32 + k] = acc;
}

// one thread per edge: histogram of obj (int atomics on 400KB L2-resident table)
__global__ void hist_kernel(const int* __restrict__ edges, int* __restrict__ counts,
                            int n_edge) {
    int e = blockIdx.x * 256 + threadIdx.x;
    if (e >= n_edge) return;
    int obj = edges[(size_t)e * 6 + 5];
    atomicAdd(&counts[obj], 1);
}

// ---- multi-block exclusive scan (counts[0..N) -> offs[0..N], cur[0..N)) ----
#define SCAN_CHUNK 1024

__global__ void scan_partial_kernel(const int* __restrict__ counts, int* __restrict__ bsum,
                                    int N) {
    __shared__ int s[256];
    int base = blockIdx.x * SCAN_CHUNK;
    int tid = threadIdx.x;
    int sum = 0;
#pragma unroll
    for (int k = 0; k < 4; ++k) {
        int idx = base + k * 256 + tid;
        if (idx < N) sum += counts[idx];
    }
    s[tid] = sum;
    __syncthreads();
    for (int off = 128; off > 0; off >>= 1) {
        if (tid < off) s[tid] += s[tid + off];
        __syncthreads();
    }
    if (tid == 0) bsum[blockIdx.x] = s[0];
}

__global__ void scan_bsum_kernel(int* __restrict__ bsum, int* __restrict__ offs, int B, int N) {
    __shared__ int s[1024];
    int tid = threadIdx.x;
    int v = (tid < B) ? bsum[tid] : 0;
    s[tid] = v;
    __syncthreads();
    for (int off = 1; off < 1024; off <<= 1) {
        int t = (tid >= off) ? s[tid - off] : 0;
        __syncthreads();
        s[tid] += t;
        __syncthreads();
    }
    if (tid < B) bsum[tid] = s[tid] - v;   // exclusive block prefix
    if (tid == 0) offs[N] = s[1023];       // grand total
}

__global__ void scan_final_kernel(const int* __restrict__ counts, const int* __restrict__ bsum,
                                  int* __restrict__ offs, int* __restrict__ cur, int N) {
    __shared__ int s[256];
    int base = blockIdx.x * SCAN_CHUNK;
    int tid = threadIdx.x;
    int v[4];
    int sum = 0;
#pragma unroll
    for (int k = 0; k < 4; ++k) {
        int idx = base + tid * 4 + k;
        v[k] = (idx < N) ? counts[idx] : 0;
        sum += v[k];
    }
    s[tid] = sum;
    __syncthreads();
    for (int off = 1; off < 256; off <<= 1) {
        int t = (tid >= off) ? s[tid - off] : 0;
        __syncthreads();
        s[tid] += t;
        __syncthreads();
    }
    int run = bsum[blockIdx.x] + s[tid] - sum;
#pragma unroll
    for (int k = 0; k < 4; ++k) {
        int idx = base + tid * 4 + k;
        if (idx < N) { offs[idx] = run; cur[idx] = run; }
        run += v[k];
    }
}

// 16 lanes per edge: compute alpha and scatter the record in one pass.
__global__ void alpha_scatter_kernel(const int* __restrict__ edges,
                                     const float2* __restrict__ S2,
                                     const float2* __restrict__ R2,
                                     const float2* __restrict__ Q2,
                                     const float2* __restrict__ w2,
                                     const float* __restrict__ w_alpha_b,
                                     int* __restrict__ cur, float2* __restrict__ rec,
                                     int n_edge) {
    int tid = threadIdx.x;
    int lane = tid & 15;
    int e = blockIdx.x * 16 + (tid >> 4);
    if (e >= n_edge) return;
    const int2* er = (const int2*)(edges + (size_t)e * 6);
    int ridx = er[0].x;
    int2 e23 = er[1];   // {rel, pad}
    int2 e45 = er[2];   // {sub, obj}
    int rel = e23.x;
    int sub = e45.x;
    int obj = e45.y;
    float2 s = S2[(size_t)sub * 16 + lane];
    float2 r = R2[(size_t)rel * 16 + lane];
    float2 q = Q2[ridx * 16 + lane];
    float a0 = fmaxf(s.x + r.x + q.x, 0.f);
    float a1 = fmaxf(s.y + r.y + q.y, 0.f);
    float2 w = w2[lane];
    float p = a0 * w.x + a1 * w.y;
#pragma unroll
    for (int off = 8; off > 0; off >>= 1) p += __shfl_xor(p, off, 16);
    if (lane == 0) {
        float alpha = 1.f / (1.f + __expf(-(p + w_alpha_b[0])));
        int pos = atomicAdd(&cur[obj], 1);
        float2 out;
        out.x = alpha;
        out.y = __int_as_float(sub | (rel << 17));  // sub<2^17, rel<2^9
        rec[pos] = out;
    }
}

// one 64-lane wave per node (lane = output dim); plain store, no atomics
__global__ void reduce_kernel(const float2* __restrict__ rec, const int* __restrict__ offs,
                              const float* __restrict__ hidden, const float* __restrict__ rela,
                              float* __restrict__ out, int n_node) {
    int lane = threadIdx.x & 63;
    int node = blockIdx.x * 4 + (threadIdx.x >> 6);
    if (node >= n_node) return;
    int start = offs[node], end = offs[node + 1];
    float acc0 = 0.f, acc1 = 0.f;
    for (int i = start; i < end; i += 64) {
        int m = end - i;
        if (m > 64) m = 64;
        float a = 0.f;
        int pk = 0;
        if (lane < m) {
            float2 r = rec[i + lane];
            a = r.x;
            pk = __float_as_int(r.y);
        }
        int j = 0;
        for (; j + 1 < m; j += 2) {
            float aj0 = __shfl(a, j, 64);
            int pkj0 = __shfl(pk, j, 64);
            float aj1 = __shfl(a, j + 1, 64);
            int pkj1 = __shfl(pk, j + 1, 64);
            int sub0 = pkj0 & 0x1FFFF, rel0 = pkj0 >> 17;
            int sub1 = pkj1 & 0x1FFFF, rel1 = pkj1 >> 17;
            acc0 += aj0 * (hidden[(size_t)sub0 * 64 + lane] + rela[(size_t)rel0 * 64 + lane]);
            acc1 += aj1 * (hidden[(size_t)sub1 * 64 + lane] + rela[(size_t)rel1 * 64 + lane]);
        }
        if (j < m) {
            float aj = __shfl(a, j, 64);
            int pkj = __shfl(pk, j, 64);
            int sub = pkj & 0x1FFFF, rel = pkj >> 17;
            acc0 += aj * (hidden[(size_t)sub * 64 + lane] + rela[(size_t)rel * 64 + lane]);
        }
    }
    out[(size_t)node * 64 + lane] = acc0 + acc1;
}

// in-place: io rows <- io rows @ Wh.T  (32 rows per block, staged through LDS)
__global__ void outgemm_inplace_kernel(const float* __restrict__ Wh, float* __restrict__ io,
                                       int n_node) {
    __shared__ float wT[64 * 64];   // wT[d*64+j] = Wh[j*64+d]
    __shared__ float arows[4 * 64];
    int tid = threadIdx.x;
    for (int i = tid; i < 64 * 64; i += 256) {
        int j = i >> 6, d = i & 63;
        wT[d * 64 + j] = Wh[i];
    }
    int r = tid >> 6, j = tid & 63;
    for (int g = 0; g < 8; ++g) {
        int gbase = blockIdx.x * 32 + g * 4;
        __syncthreads();
        if ((size_t)gbase * 64 + tid < (size_t)n_node * 64)
            arows[tid] = io[(size_t)gbase * 64 + tid];
        __syncthreads();
        int row = gbase + r;
        if (row < n_node) {
            float acc = 0.f;
#pragma unroll
            for (int d4 = 0; d4 < 16; ++d4) {
                int d = d4 * 4;
                float4 m4 = *(const float4*)&arows[r * 64 + d];
                acc += m4.x * wT[(d + 0) * 64 + j] + m4.y * wT[(d + 1) * 64 + j]
                     + m4.z * wT[(d + 2) * 64 + j] + m4.w * wT[(d + 3) * 64 + j];
            }
            io[(size_t)row * 64 + j] = acc;
        }
    }
}

extern "C" void kernel_launch(void* const* d_in, const int* in_sizes, int n_in,
                              void* d_out, int out_size, void* d_ws, size_t ws_size,
                              hipStream_t stream) {
    const int*   q_rel     = (const int*)d_in[1];
    const float* hidden    = (const float*)d_in[2];
    const int*   edges     = (const int*)d_in[3];
    const float* rela      = (const float*)d_in[7];
    const float* Ws        = (const float*)d_in[8];
    const float* Wr        = (const float*)d_in[9];
    const float* Wqr       = (const float*)d_in[10];
    const float* bqr       = (const float*)d_in[11];
    const float* w_alpha_w = (const float*)d_in[12];
    const float* w_alpha_b = (const float*)d_in[13];
    const float* Wh        = (const float*)d_in[14];

    int n_node = in_sizes[2] / 64;
    int n_edge = in_sizes[3] / 6;
    int n_rel  = in_sizes[7] / 64;
    int batch  = in_sizes[1];

    int n_sblk = (n_node + SCAN_CHUNK - 1) / SCAN_CHUNK;   // scan blocks (<=1024)

    // workspace layout (~30 MB)
    float* S      = (float*)d_ws;                         // n_node*32
    float* R      = S + (size_t)n_node * 32;              // n_rel*32
    float* Q      = R + (size_t)n_rel * 32;               // batch*32
    int*   counts = (int*)(Q + (size_t)batch * 32);       // n_node
    int*   offs   = counts + n_node;                      // n_node+1
    int*   cur    = offs + n_node + 1;                    // n_node
    int*   bsum   = cur + n_node;                         // n_sblk
    size_t rec_off = (size_t)(bsum + n_sblk - (int*)d_ws);
    rec_off = (rec_off + 3) & ~(size_t)3;                 // align 16B
    float2* rec   = (float2*)((int*)d_ws + rec_off);      // n_edge float2

    (void)hipMemsetAsync(counts, 0, (size_t)n_node * sizeof(int), stream);

    proj32_kernel<<<(n_node + 7) / 8, 256, 0, stream>>>(hidden, Ws, S, n_node);
    proj32_kernel<<<(n_rel + 7) / 8, 256, 0, stream>>>(rela, Wr, R, n_rel);
    qproj_kernel<<<1, 256, 0, stream>>>(q_rel, rela, Wqr, bqr, Q, batch);

    hist_kernel<<<(n_edge + 255) / 256, 256, 0, stream>>>(edges, counts, n_edge);

    scan_partial_kernel<<<n_sblk, 256, 0, stream>>>(counts, bsum, n_node);
    scan_bsum_kernel<<<1, 1024, 0, stream>>>(bsum, offs, n_sblk, n_node);
    scan_final_kernel<<<n_sblk, 256, 0, stream>>>(counts, bsum, offs, cur, n_node);

    alpha_scatter_kernel<<<(n_edge + 15) / 16, 256, 0, stream>>>(
        edges, (const float2*)S, (const float2*)R, (const float2*)Q,
        (const float2*)w_alpha_w, w_alpha_b, cur, rec, n_edge);

    reduce_kernel<<<(n_node + 3) / 4, 256, 0, stream>>>(rec, offs, hidden, rela,
                                                        (float*)d_out, n_node);
    outgemm_inplace_kernel<<<(n_node + 31) / 32, 256, 0, stream>>>(Wh, (float*)d_out, n_node);
}

// Round 7
// 550.242 us; speedup vs baseline: 2.1861x; 1.0361x over previous
//
#include <hip/hip_runtime.h>
#include <hip/hip_bf16.h>

// Atomic-free aggregation via counting-sort by obj:
//   S = hidden @ Ws.T, R = rela @ Wr.T, Q[b] = rela[q_rel[b]] @ Wqr.T + bqr
//   hist: counts[obj]++                                   (int atomics, L2-resident)
//   multi-block exclusive scan of counts -> offs/cur
//   alpha+scatter fused: alpha = sigmoid(...); pos = cur[obj]++;
//                        rec[pos] = {alpha, sub|rel<<17}   (8B records, no f32 RMW)
//   reduce: per node, sum alpha*(hidden[sub]+rela[rel]) over its segment -> d_out
//           (4 records in flight per wave, float4 gathers)
//   outgemm_inplace: d_out rows <- d_out rows @ Wh.T       (barrier-free row stream)

__global__ void proj32_kernel(const float* __restrict__ X, const float* __restrict__ W,
                              float* __restrict__ out, int nrows) {
    // out[n][k] = sum_d X[n][d] * W[k][d],  k<32, d<64
    __shared__ float wT[64 * 32];
    int tid = threadIdx.x;
    for (int i = tid; i < 32 * 64; i += 256) {
        int k = i >> 6, d = i & 63;
        wT[d * 32 + k] = W[i];
    }
    __syncthreads();
    int row = blockIdx.x * 8 + (tid >> 5);
    int k = tid & 31;
    if (row >= nrows) return;
    const float4* X4 = (const float4*)(X + (size_t)row * 64);
    float acc = 0.f;
#pragma unroll
    for (int d4 = 0; d4 < 16; ++d4) {
        float4 x = X4[d4];
        int d = d4 * 4;
        acc += x.x * wT[(d + 0) * 32 + k] + x.y * wT[(d + 1) * 32 + k]
             + x.z * wT[(d + 2) * 32 + k] + x.w * wT[(d + 3) * 32 + k];
    }
    out[(size_t)row * 32 + k] = acc;
}

__global__ void qproj_kernel(const int* __restrict__ q_rel, const float* __restrict__ rela,
                             const float* __restrict__ Wqr, const float* __restrict__ bqr,
                             float* __restrict__ Q, int batch) {
    int tid = threadIdx.x;
    int b = tid >> 5, k = tid & 31;
    if (b >= batch) return;
    int qr = q_rel[b];
    const float* x = rela + (size_t)qr * 64;
    const float* w = Wqr + (size_t)k * 64;
    float acc = bqr[k];
    for (int d = 0; d < 64; ++d) acc += w[d] * x[d];
    Q[b * 32 + k] = acc;
}

// one thread per edge: histogram of obj (int atomics on 400KB L2-resident table)
__global__ void hist_kernel(const int* __restrict__ edges, int* __restrict__ counts,
                            int n_edge) {
    int e = blockIdx.x * 256 + threadIdx.x;
    if (e >= n_edge) return;
    int obj = edges[(size_t)e * 6 + 5];
    atomicAdd(&counts[obj], 1);
}

// ---- multi-block exclusive scan (counts[0..N) -> offs[0..N], cur[0..N)) ----
#define SCAN_CHUNK 1024

__global__ void scan_partial_kernel(const int* __restrict__ counts, int* __restrict__ bsum,
                                    int N) {
    __shared__ int s[256];
    int base = blockIdx.x * SCAN_CHUNK;
    int tid = threadIdx.x;
    int sum = 0;
#pragma unroll
    for (int k = 0; k < 4; ++k) {
        int idx = base + k * 256 + tid;
        if (idx < N) sum += counts[idx];
    }
    s[tid] = sum;
    __syncthreads();
    for (int off = 128; off > 0; off >>= 1) {
        if (tid < off) s[tid] += s[tid + off];
        __syncthreads();
    }
    if (tid == 0) bsum[blockIdx.x] = s[0];
}

__global__ void scan_bsum_kernel(int* __restrict__ bsum, int* __restrict__ offs, int B, int N) {
    __shared__ int s[1024];
    int tid = threadIdx.x;
    int v = (tid < B) ? bsum[tid] : 0;
    s[tid] = v;
    __syncthreads();
    for (int off = 1; off < 1024; off <<= 1) {
        int t = (tid >= off) ? s[tid - off] : 0;
        __syncthreads();
        s[tid] += t;
        __syncthreads();
    }
    if (tid < B) bsum[tid] = s[tid] - v;   // exclusive block prefix
    if (tid == 0) offs[N] = s[1023];       // grand total
}

__global__ void scan_final_kernel(const int* __restrict__ counts, const int* __restrict__ bsum,
                                  int* __restrict__ offs, int* __restrict__ cur, int N) {
    __shared__ int s[256];
    int base = blockIdx.x * SCAN_CHUNK;
    int tid = threadIdx.x;
    int v[4];
    int sum = 0;
#pragma unroll
    for (int k = 0; k < 4; ++k) {
        int idx = base + tid * 4 + k;
        v[k] = (idx < N) ? counts[idx] : 0;
        sum += v[k];
    }
    s[tid] = sum;
    __syncthreads();
    for (int off = 1; off < 256; off <<= 1) {
        int t = (tid >= off) ? s[tid - off] : 0;
        __syncthreads();
        s[tid] += t;
        __syncthreads();
    }
    int run = bsum[blockIdx.x] + s[tid] - sum;
#pragma unroll
    for (int k = 0; k < 4; ++k) {
        int idx = base + tid * 4 + k;
        if (idx < N) { offs[idx] = run; cur[idx] = run; }
        run += v[k];
    }
}

// 16 lanes per edge: compute alpha and scatter the record in one pass.
__global__ void alpha_scatter_kernel(const int* __restrict__ edges,
                                     const float2* __restrict__ S2,
                                     const float2* __restrict__ R2,
                                     const float2* __restrict__ Q2,
                                     const float2* __restrict__ w2,
                                     const float* __restrict__ w_alpha_b,
                                     int* __restrict__ cur, float2* __restrict__ rec,
                                     int n_edge) {
    int tid = threadIdx.x;
    int lane = tid & 15;
    int e = blockIdx.x * 16 + (tid >> 4);
    if (e >= n_edge) return;
    const int2* er = (const int2*)(edges + (size_t)e * 6);
    int ridx = er[0].x;
    int2 e23 = er[1];   // {rel, pad}
    int2 e45 = er[2];   // {sub, obj}
    int rel = e23.x;
    int sub = e45.x;
    int obj = e45.y;
    float2 s = S2[(size_t)sub * 16 + lane];
    float2 r = R2[(size_t)rel * 16 + lane];
    float2 q = Q2[ridx * 16 + lane];
    float a0 = fmaxf(s.x + r.x + q.x, 0.f);
    float a1 = fmaxf(s.y + r.y + q.y, 0.f);
    float2 w = w2[lane];
    float p = a0 * w.x + a1 * w.y;
#pragma unroll
    for (int off = 8; off > 0; off >>= 1) p += __shfl_xor(p, off, 16);
    if (lane == 0) {
        float alpha = 1.f / (1.f + __expf(-(p + w_alpha_b[0])));
        int pos = atomicAdd(&cur[obj], 1);
        float2 out;
        out.x = alpha;
        out.y = __int_as_float(sub | (rel << 17));  // sub<2^17, rel<2^9
        rec[pos] = out;
    }
}

// one 64-lane wave per node; 4 records in flight (groups of 16 lanes, float4 loads)
__global__ void reduce_kernel(const float2* __restrict__ rec, const int* __restrict__ offs,
                              const float4* __restrict__ hidden4,
                              const float4* __restrict__ rela4,
                              float4* __restrict__ out4, int n_node) {
    int lane = threadIdx.x & 63;
    int node = blockIdx.x * 4 + (threadIdx.x >> 6);
    if (node >= n_node) return;
    int g = lane >> 4;        // record subgroup 0..3
    int t = lane & 15;        // dim-quad index 0..15
    int start = offs[node], end = offs[node + 1];
    float4 acc = make_float4(0.f, 0.f, 0.f, 0.f);
    for (int i = start; i < end; i += 64) {
        int m = end - i;
        if (m > 64) m = 64;
        float a = 0.f;        // a=0 for idle lanes -> tail records contribute 0
        int pk = 0;
        if (lane < m) {
            float2 r = rec[i + lane];
            a = r.x;
            pk = __float_as_int(r.y);
        }
        for (int j = 0; 4 * j < m; ++j) {
            int src = 4 * j + g;
            float aj = __shfl(a, src, 64);
            int pkj = __shfl(pk, src, 64);
            int sub = pkj & 0x1FFFF, rel = pkj >> 17;
            float4 h = hidden4[(size_t)sub * 16 + t];
            float4 rr = rela4[(size_t)rel * 16 + t];
            acc.x += aj * (h.x + rr.x);
            acc.y += aj * (h.y + rr.y);
            acc.z += aj * (h.z + rr.z);
            acc.w += aj * (h.w + rr.w);
        }
    }
    // fold the 4 record-groups (same t, different g) via butterfly over bits 4,5
#pragma unroll
    for (int off = 16; off <= 32; off <<= 1) {
        acc.x += __shfl_xor(acc.x, off, 64);
        acc.y += __shfl_xor(acc.y, off, 64);
        acc.z += __shfl_xor(acc.z, off, 64);
        acc.w += __shfl_xor(acc.w, off, 64);
    }
    if (g == 0) out4[(size_t)node * 16 + t] = acc;
}

// in-place: io rows <- io rows @ Wh.T; rows streamed via wave-uniform float4 loads
__global__ void outgemm_inplace_kernel(const float* __restrict__ Wh, float* __restrict__ io,
                                       int n_node) {
    __shared__ float wT[64 * 64];   // wT[d*64+j] = Wh[j*64+d]
    int tid = threadIdx.x;
    for (int i = tid; i < 64 * 64; i += 256) {
        int j = i >> 6, d = i & 63;
        wT[d * 64 + j] = Wh[i];
    }
    __syncthreads();
    int wave = tid >> 6, j = tid & 63;
    int base = blockIdx.x * 32;              // 32 rows per block, 8 per wave
    for (int r = wave; r < 32; r += 4) {
        int row = base + r;
        if (row >= n_node) break;
        const float4* rp = (const float4*)(io + (size_t)row * 64);
        float acc = 0.f;
#pragma unroll
        for (int d4 = 0; d4 < 16; ++d4) {
            float4 m4 = rp[d4];              // wave-uniform broadcast load (L1)
            int d = d4 * 4;
            acc += m4.x * wT[(d + 0) * 64 + j] + m4.y * wT[(d + 1) * 64 + j]
                 + m4.z * wT[(d + 2) * 64 + j] + m4.w * wT[(d + 3) * 64 + j];
        }
        io[(size_t)row * 64 + j] = acc;      // same wave read the row fully first
    }
}

extern "C" void kernel_launch(void* const* d_in, const int* in_sizes, int n_in,
                              void* d_out, int out_size, void* d_ws, size_t ws_size,
                              hipStream_t stream) {
    const int*   q_rel     = (const int*)d_in[1];
    const float* hidden    = (const float*)d_in[2];
    const int*   edges     = (const int*)d_in[3];
    const float* rela      = (const float*)d_in[7];
    const float* Ws        = (const float*)d_in[8];
    const float* Wr        = (const float*)d_in[9];
    const float* Wqr       = (const float*)d_in[10];
    const float* bqr       = (const float*)d_in[11];
    const float* w_alpha_w = (const float*)d_in[12];
    const float* w_alpha_b = (const float*)d_in[13];
    const float* Wh        = (const float*)d_in[14];

    int n_node = in_sizes[2] / 64;
    int n_edge = in_sizes[3] / 6;
    int n_rel  = in_sizes[7] / 64;
    int batch  = in_sizes[1];

    int n_sblk = (n_node + SCAN_CHUNK - 1) / SCAN_CHUNK;   // scan blocks (<=1024)

    // workspace layout (~30 MB)
    float* S      = (float*)d_ws;                         // n_node*32
    float* R      = S + (size_t)n_node * 32;              // n_rel*32
    float* Q      = R + (size_t)n_rel * 32;               // batch*32
    int*   counts = (int*)(Q + (size_t)batch * 32);       // n_node
    int*   offs   = counts + n_node;                      // n_node+1
    int*   cur    = offs + n_node + 1;                    // n_node
    int*   bsum   = cur + n_node;                         // n_sblk
    size_t rec_off = (size_t)(bsum + n_sblk - (int*)d_ws);
    rec_off = (rec_off + 3) & ~(size_t)3;                 // align 16B
    float2* rec   = (float2*)((int*)d_ws + rec_off);      // n_edge float2

    (void)hipMemsetAsync(counts, 0, (size_t)n_node * sizeof(int), stream);

    proj32_kernel<<<(n_node + 7) / 8, 256, 0, stream>>>(hidden, Ws, S, n_node);
    proj32_kernel<<<(n_rel + 7) / 8, 256, 0, stream>>>(rela, Wr, R, n_rel);
    qproj_kernel<<<1, 256, 0, stream>>>(q_rel, rela, Wqr, bqr, Q, batch);

    hist_kernel<<<(n_edge + 255) / 256, 256, 0, stream>>>(edges, counts, n_edge);

    scan_partial_kernel<<<n_sblk, 256, 0, stream>>>(counts, bsum, n_node);
    scan_bsum_kernel<<<1, 1024, 0, stream>>>(bsum, offs, n_sblk, n_node);
    scan_final_kernel<<<n_sblk, 256, 0, stream>>>(counts, bsum, offs, cur, n_node);

    alpha_scatter_kernel<<<(n_edge + 15) / 16, 256, 0, stream>>>(
        edges, (const float2*)S, (const float2*)R, (const float2*)Q,
        (const float2*)w_alpha_w, w_alpha_b, cur, rec, n_edge);

    reduce_kernel<<<(n_node + 3) / 4, 256, 0, stream>>>(
        rec, offs, (const float4*)hidden, (const float4*)rela, (float4*)d_out, n_node);
    outgemm_inplace_kernel<<<(n_node + 31) / 32, 256, 0, stream>>>(Wh, (float*)d_out, n_node);
}